// Round 3
// baseline (357.171 us; speedup 1.0000x reference)
//
#include <hip/hip_runtime.h>

typedef __bf16 bf16x8 __attribute__((ext_vector_type(8)));
typedef float f32x4 __attribute__((ext_vector_type(4)));
typedef short short4v __attribute__((ext_vector_type(4)));
typedef short short8v __attribute__((ext_vector_type(8)));

#define DEVI static __device__ __forceinline__

// fp32 -> bf16 bits, round-to-nearest-even
DEVI short f2bf(float f) {
    union { float f; unsigned u; } x; x.f = f;
    unsigned r = (x.u + 0x7fffu + ((x.u >> 16) & 1u)) >> 16;
    return (short)r;
}

// async global -> LDS, 16B per lane (dest linear: wave-uniform base + lane*16)
DEVI void gld16(const void* g, void* l) {
    __builtin_amdgcn_global_load_lds(
        (const __attribute__((address_space(1))) unsigned int*)g,
        (__attribute__((address_space(3))) unsigned int*)l, 16, 0, 0);
}

// ---------------- x fp32 -> bf16 ----------------
__global__ __launch_bounds__(256) void cvt_x_kernel(const float* __restrict__ x,
                                                    short* __restrict__ xb) {
    int i = (blockIdx.x * 256 + threadIdx.x) * 8;
    f32x4 a = *(const f32x4*)(x + i);
    f32x4 b = *(const f32x4*)(x + i + 4);
    short8v o;
    o[0]=f2bf(a[0]); o[1]=f2bf(a[1]); o[2]=f2bf(a[2]); o[3]=f2bf(a[3]);
    o[4]=f2bf(b[0]); o[5]=f2bf(b[1]); o[6]=f2bf(b[2]); o[7]=f2bf(b[3]);
    *(short8v*)(xb + i) = o;
}

// ------------- weight [K=1024][N=1024] fp32 -> [N][K] bf16 (transpose) -------------
__global__ __launch_bounds__(256) void wtrans_kernel(const float* __restrict__ w,
                                                     short* __restrict__ wt) {
    __shared__ float t[64][68];
    const int tid = threadIdx.x;
    const int k0 = blockIdx.x * 64, n0 = blockIdx.y * 64;
#pragma unroll
    for (int it = 0; it < 4; ++it) {
        int r = (tid >> 4) + it * 16;
        int cc = (tid & 15) * 4;
        f32x4 vv = *(const f32x4*)(w + (k0 + r) * 1024 + n0 + cc);
        *(f32x4*)&t[r][cc] = vv;
    }
    __syncthreads();
#pragma unroll
    for (int it = 0; it < 4; ++it) {
        int n = (tid >> 4) + it * 16;
        int kc = (tid & 15) * 4;
        short4v o;
        o[0] = f2bf(t[kc + 0][n]);
        o[1] = f2bf(t[kc + 1][n]);
        o[2] = f2bf(t[kc + 2][n]);
        o[3] = f2bf(t[kc + 3][n]);
        *(short4v*)(wt + (n0 + n) * 1024 + k0 + kc) = o;
    }
}

// ---------------- GEMM: C[M,N] = A[M,1024] @ Bt[N,1024]^T (m97 structure, linear LDS) --------
// MODE 0: scatter bf16 to q/k/v [which][b*16+h][t][64]   (outp = qkv base)
// MODE 1: bf16 out = acc + bias
// MODE 2: fp32 out = relu(acc + bias)
template<int MODE>
__global__ __launch_bounds__(256, 2) void gemm_bt(const short* __restrict__ A,
                                                  const short* __restrict__ Bt,
                                                  const float* __restrict__ bias,
                                                  void* __restrict__ outp) {
    __shared__ short As[128 * 64];  // [row][k] linear, 64 shorts/row
    __shared__ short Bs[128 * 64];
    const int tid = threadIdx.x;
    const int lane = tid & 63;
    const int wid = tid >> 6;
    const int g = lane >> 4, c = lane & 15;
    const int wr = wid >> 1, wc = wid & 1;
    const int m0 = blockIdx.x * 128, n0 = blockIdx.y * 128;

    const f32x4 fz = {0.f, 0.f, 0.f, 0.f};
    f32x4 acc[4][4];
#pragma unroll
    for (int m = 0; m < 4; ++m)
#pragma unroll
        for (int n = 0; n < 4; ++n) acc[m][n] = fz;

    for (int kt = 0; kt < 16; ++kt) {
        const int k0 = kt * 64;
        __syncthreads();
#pragma unroll
        for (int st = 0; st < 4; ++st) {
            int ci = st * 256 + tid;
            int r = ci >> 3;
            int cc = (ci & 7) << 3;             // linear source column (no swizzle)
            gld16(A + (m0 + r) * 1024 + k0 + cc, (char*)As + ci * 16);
            gld16(Bt + (n0 + r) * 1024 + k0 + cc, (char*)Bs + ci * 16);
        }
        __syncthreads();
#pragma unroll
        for (int kk = 0; kk < 2; ++kk) {
            bf16x8 af[4], bfr[4];
#pragma unroll
            for (int m = 0; m < 4; ++m) {
                int row = wr * 64 + m * 16 + c;
                af[m] = *(const bf16x8*)&As[row * 64 + kk * 32 + g * 8];
            }
#pragma unroll
            for (int n = 0; n < 4; ++n) {
                int row = wc * 64 + n * 16 + c;
                bfr[n] = *(const bf16x8*)&Bs[row * 64 + kk * 32 + g * 8];
            }
#pragma unroll
            for (int m = 0; m < 4; ++m)
#pragma unroll
                for (int n = 0; n < 4; ++n)
                    acc[m][n] = __builtin_amdgcn_mfma_f32_16x16x32_bf16(af[m], bfr[n], acc[m][n], 0, 0, 0);
        }
    }

#pragma unroll
    for (int n = 0; n < 4; ++n) {
        const int col = n0 + wc * 64 + n * 16 + c;
        float bv = 0.f;
        if (MODE != 0) bv = bias[col];
#pragma unroll
        for (int m = 0; m < 4; ++m) {
            const int row0 = m0 + wr * 64 + m * 16 + g * 4;
#pragma unroll
            for (int i = 0; i < 4; ++i) {
                const int row = row0 + i;
                float val = acc[m][n][i];
                if (MODE == 0) {
                    short* qkv = (short*)outp;
                    int which = col >> 10;
                    int hc = col & 1023;
                    int dst = which * 8388608 +
                              (((row >> 10) * 16 + (hc >> 6)) * 1024 + (row & 1023)) * 64 + (hc & 63);
                    qkv[dst] = f2bf(val);
                } else if (MODE == 1) {
                    ((short*)outp)[row * 1024 + col] = f2bf(val + bv);
                } else {
                    ((float*)outp)[row * 1024 + col] = fmaxf(val + bv, 0.f);
                }
            }
        }
    }
}

// ---------------- causal flash attention v2 ----------------
// grid (T/128, B*H), 512 threads / 8 waves. Each wave: 16 q-rows. K tiles of 128.
// All LDS buffers XOR-swizzled (same formula on write and read; reg-staged).
__global__ __launch_bounds__(512, 4) void attn_kernel(const short* __restrict__ qp,
                                                      const short* __restrict__ kp,
                                                      const short* __restrict__ vp,
                                                      short* __restrict__ ao) {
    __shared__ short Ks[128 * 64];     // row t: 128B rows, swz ((r&7)<<4)
    __shared__ short Vt[64 * 128];     // row d: 256B rows, swz (((d&7)^(d>>3))<<4)
    __shared__ short Ps[8][16 * 128];  // per-wave, row q: 256B rows, swz ((q&7)<<4)
    const float SCALE = 0.125f * 1.44269504088896340736f;  // 1/sqrt(64) * log2(e)
    const int tid = threadIdx.x;
    const int lane = tid & 63;
    const int wid = tid >> 6;
    const int g = lane >> 4, c = lane & 15;
    const int qt = blockIdx.x, bh = blockIdx.y;
    const int q0 = qt * 128;
    const int base = bh * 65536;  // 1024*64

    // Q A-fragments hoisted to registers (rows q0 + wid*16 + c)
    const int qrow = q0 + wid * 16 + c;
    bf16x8 qf0 = *(const bf16x8*)(qp + base + qrow * 64 + g * 8);
    bf16x8 qf1 = *(const bf16x8*)(qp + base + qrow * 64 + 32 + g * 8);

    const f32x4 fz = {0.f, 0.f, 0.f, 0.f};
    f32x4 accO[4];
#pragma unroll
    for (int n = 0; n < 4; ++n) accO[n] = fz;
    float mrow[4], lrow[4];
#pragma unroll
    for (int i = 0; i < 4; ++i) { mrow[i] = -1e30f; lrow[i] = 0.f; }

    // V staging decomposition: thread handles 4t x 4d
    const int vt0 = (tid >> 4) * 4;   // 0..124
    const int vd0 = (tid & 15) * 4;   // 0..60

    const int nkt = qt + 1;
    for (int kt = 0; kt < nkt; ++kt) {
        __syncthreads();  // previous iteration's Ks/Vt reads complete
        // ---- stage K (reg -> LDS, swizzled) ----
#pragma unroll
        for (int it = 0; it < 2; ++it) {
            int ci = it * 512 + tid;
            int r = ci >> 3;
            int cc = (ci & 7) << 3;
            bf16x8 kv = *(const bf16x8*)(kp + base + (kt * 128 + r) * 64 + cc);
            *(bf16x8*)((char*)Ks + r * 128 + ((cc * 2) ^ ((r & 7) << 4))) = kv;
        }
        // ---- stage V transposed (4x4 register transpose, b64 stores) ----
        {
            short4v vv[4];
#pragma unroll
            for (int j = 0; j < 4; ++j)
                vv[j] = *(const short4v*)(vp + base + (kt * 128 + vt0 + j) * 64 + vd0);
#pragma unroll
            for (int i = 0; i < 4; ++i) {
                short4v w; w[0] = vv[0][i]; w[1] = vv[1][i]; w[2] = vv[2][i]; w[3] = vv[3][i];
                int d = vd0 + i;
                int swz = ((d & 7) ^ (d >> 3)) << 4;
                *(short4v*)((char*)Vt + d * 256 + ((vt0 * 2) ^ swz)) = w;
            }
        }
        __syncthreads();  // staging visible to all waves

        // ---- S = Q K^T  (16 q-rows x 128 keys per wave) ----
        f32x4 s[8];
#pragma unroll
        for (int n = 0; n < 8; ++n) {
            s[n] = fz;
            int row = n * 16 + c;
            int swz = (row & 7) << 4;
            bf16x8 kf0 = *(const bf16x8*)((const char*)Ks + row * 128 + ((g * 16) ^ swz));
            bf16x8 kf1 = *(const bf16x8*)((const char*)Ks + row * 128 + ((64 + g * 16) ^ swz));
            s[n] = __builtin_amdgcn_mfma_f32_16x16x32_bf16(qf0, kf0, s[n], 0, 0, 0);
            s[n] = __builtin_amdgcn_mfma_f32_16x16x32_bf16(qf1, kf1, s[n], 0, 0, 0);
        }

        // ---- scale + causal mask + per-row max ----
        const int qg0 = q0 + wid * 16 + g * 4;
        float pm[4];
#pragma unroll
        for (int i = 0; i < 4; ++i) pm[i] = -1e30f;
#pragma unroll
        for (int n = 0; n < 8; ++n) {
            int kg = kt * 128 + n * 16 + c;
#pragma unroll
            for (int i = 0; i < 4; ++i) {
                float vv = s[n][i] * SCALE;
                vv = (kg <= qg0 + i) ? vv : -1e30f;
                s[n][i] = vv;
                pm[i] = fmaxf(pm[i], vv);
            }
        }
#pragma unroll
        for (int off = 1; off < 16; off <<= 1)
#pragma unroll
            for (int i = 0; i < 4; ++i)
                pm[i] = fmaxf(pm[i], __shfl_xor(pm[i], off));

        // ---- online softmax update ----
        float rs[4];
#pragma unroll
        for (int i = 0; i < 4; ++i) {
            float mnew = fmaxf(mrow[i], pm[i]);
            float corr = exp2f(mrow[i] - mnew);
            mrow[i] = mnew;
            lrow[i] *= corr;
            rs[i] = 0.f;
#pragma unroll
            for (int n = 0; n < 4; ++n) accO[n][i] *= corr;
        }
#pragma unroll
        for (int n = 0; n < 8; ++n)
#pragma unroll
            for (int i = 0; i < 4; ++i) {
                float pv = exp2f(s[n][i] - mrow[i]);
                s[n][i] = pv;
                rs[i] += pv;
            }
#pragma unroll
        for (int off = 1; off < 16; off <<= 1)
#pragma unroll
            for (int i = 0; i < 4; ++i)
                rs[i] += __shfl_xor(rs[i], off);
#pragma unroll
        for (int i = 0; i < 4; ++i) lrow[i] += rs[i];

        // ---- write P to per-wave LDS [q][t] (swizzled scalar stores) ----
#pragma unroll
        for (int n = 0; n < 8; ++n) {
            int t = n * 16 + c;
#pragma unroll
            for (int i = 0; i < 4; ++i) {
                int q = g * 4 + i;
                *(short*)((char*)&Ps[wid][0] + q * 256 + ((t * 2) ^ ((q & 7) << 4))) = f2bf(s[n][i]);
            }
        }

        // ---- O += P @ V ----
#pragma unroll
        for (int ks = 0; ks < 4; ++ks) {
            bf16x8 paf = *(const bf16x8*)((const char*)&Ps[wid][0] +
                                          c * 256 + ((ks * 64 + g * 16) ^ ((c & 7) << 4)));
#pragma unroll
            for (int n = 0; n < 4; ++n) {
                int d = n * 16 + c;
                int swz = ((d & 7) ^ (d >> 3)) << 4;
                bf16x8 vf = *(const bf16x8*)((const char*)Vt + d * 256 + ((ks * 64 + g * 16) ^ swz));
                accO[n] = __builtin_amdgcn_mfma_f32_16x16x32_bf16(paf, vf, accO[n], 0, 0, 0);
            }
        }
    }

    // epilogue: normalize, store bf16 to [B, T, H*64+d]
    const int b = bh >> 4, h = bh & 15;
#pragma unroll
    for (int n = 0; n < 4; ++n)
#pragma unroll
        for (int i = 0; i < 4; ++i) {
            int t = q0 + wid * 16 + g * 4 + i;
            float o = accO[n][i] / lrow[i];
            ao[(b * 1024 + t) * 1024 + h * 64 + n * 16 + c] = f2bf(o);
        }
}

extern "C" void kernel_launch(void* const* d_in, const int* in_sizes, int n_in,
                              void* d_out, int out_size, void* d_ws, size_t ws_size,
                              hipStream_t stream) {
    const float* x  = (const float*)d_in[0];
    const float* Wq = (const float*)d_in[1];
    const float* Wk = (const float*)d_in[2];
    const float* Wv = (const float*)d_in[3];
    const float* Wo = (const float*)d_in[4];
    const float* bo = (const float*)d_in[5];
    const float* W1 = (const float*)d_in[6];
    const float* b1 = (const float*)d_in[7];

    char* ws = (char*)d_ws;
    short* xb    = (short*)(ws + 0);          // 16.78 MB  [8192][1024] bf16
    short* wqkvT = (short*)(ws + 16777216);   //  6.29 MB  [3072][1024] bf16 (Wq^T|Wk^T|Wv^T)
    short* woT   = (short*)(ws + 23068672);   //  2.10 MB
    short* w1T   = (short*)(ws + 25165824);   //  2.10 MB
    short* qb    = (short*)(ws + 27262976);   // 3 x 16.78 MB: q,k,v [B*H][T][64] bf16
    short* kb    = qb + 8388608;
    short* vb    = qb + 16777216;
    short* ao    = xb;                        // reuse: attention out [8192][1024] bf16
    short* o2    = qb;                        // reuse: Wo out [8192][1024] bf16

    cvt_x_kernel<<<4096, 256, 0, stream>>>(x, xb);
    wtrans_kernel<<<dim3(16, 16), 256, 0, stream>>>(Wq, wqkvT);
    wtrans_kernel<<<dim3(16, 16), 256, 0, stream>>>(Wk, wqkvT + 1048576);
    wtrans_kernel<<<dim3(16, 16), 256, 0, stream>>>(Wv, wqkvT + 2097152);
    wtrans_kernel<<<dim3(16, 16), 256, 0, stream>>>(Wo, woT);
    wtrans_kernel<<<dim3(16, 16), 256, 0, stream>>>(W1, w1T);

    gemm_bt<0><<<dim3(64, 24), 256, 0, stream>>>(xb, wqkvT, nullptr, (void*)qb);
    attn_kernel<<<dim3(8, 128), 512, 0, stream>>>(qb, kb, vb, ao);
    gemm_bt<1><<<dim3(64, 8), 256, 0, stream>>>(ao, woT, bo, (void*)o2);
    gemm_bt<2><<<dim3(64, 8), 256, 0, stream>>>(o2, w1T, b1, d_out);
}

// Round 4
// 273.160 us; speedup vs baseline: 1.3076x; 1.3076x over previous
//
#include <hip/hip_runtime.h>

typedef __bf16 bf16x8 __attribute__((ext_vector_type(8)));
typedef float f32x4 __attribute__((ext_vector_type(4)));
typedef short short4v __attribute__((ext_vector_type(4)));
typedef short short8v __attribute__((ext_vector_type(8)));

#define DEVI static __device__ __forceinline__

// fp32 -> bf16 bits, round-to-nearest-even
DEVI short f2bf(float f) {
    union { float f; unsigned u; } x; x.f = f;
    unsigned r = (x.u + 0x7fffu + ((x.u >> 16) & 1u)) >> 16;
    return (short)r;
}

// async global -> LDS, 16B per lane (dest linear: wave-uniform base + lane*16)
DEVI void gld16(const void* g, void* l) {
    __builtin_amdgcn_global_load_lds(
        (const __attribute__((address_space(1))) unsigned int*)g,
        (__attribute__((address_space(3))) unsigned int*)l, 16, 0, 0);
}

// ---------------- x fp32 -> bf16 ----------------
__global__ __launch_bounds__(256) void cvt_x_kernel(const float* __restrict__ x,
                                                    short* __restrict__ xb) {
    int i = (blockIdx.x * 256 + threadIdx.x) * 8;
    f32x4 a = *(const f32x4*)(x + i);
    f32x4 b = *(const f32x4*)(x + i + 4);
    short8v o;
    o[0]=f2bf(a[0]); o[1]=f2bf(a[1]); o[2]=f2bf(a[2]); o[3]=f2bf(a[3]);
    o[4]=f2bf(b[0]); o[5]=f2bf(b[1]); o[6]=f2bf(b[2]); o[7]=f2bf(b[3]);
    *(short8v*)(xb + i) = o;
}

// ------------- weight [K=1024][N=1024] fp32 -> [N][K] bf16 (transpose) -------------
__global__ __launch_bounds__(256) void wtrans_kernel(const float* __restrict__ w,
                                                     short* __restrict__ wt) {
    __shared__ float t[64][68];
    const int tid = threadIdx.x;
    const int k0 = blockIdx.x * 64, n0 = blockIdx.y * 64;
#pragma unroll
    for (int it = 0; it < 4; ++it) {
        int r = (tid >> 4) + it * 16;
        int cc = (tid & 15) * 4;
        f32x4 vv = *(const f32x4*)(w + (k0 + r) * 1024 + n0 + cc);
        *(f32x4*)&t[r][cc] = vv;
    }
    __syncthreads();
#pragma unroll
    for (int it = 0; it < 4; ++it) {
        int n = (tid >> 4) + it * 16;
        int kc = (tid & 15) * 4;
        short4v o;
        o[0] = f2bf(t[kc + 0][n]);
        o[1] = f2bf(t[kc + 1][n]);
        o[2] = f2bf(t[kc + 2][n]);
        o[3] = f2bf(t[kc + 3][n]);
        *(short4v*)(wt + (n0 + n) * 1024 + k0 + kc) = o;
    }
}

// ---------------- GEMM: C[M,N] = A[M,1024] @ Bt[N,1024]^T (m97 structure, linear LDS) --------
// MODE 0: scatter bf16 to q/k/v [which][b*16+h][t][64]   (outp = qkv base)
// MODE 1: bf16 out = acc + bias
// MODE 2: fp32 out = relu(acc + bias)
template<int MODE>
__global__ __launch_bounds__(256, 2) void gemm_bt(const short* __restrict__ A,
                                                  const short* __restrict__ Bt,
                                                  const float* __restrict__ bias,
                                                  void* __restrict__ outp) {
    __shared__ short As[128 * 64];  // [row][k] linear, 64 shorts/row
    __shared__ short Bs[128 * 64];
    const int tid = threadIdx.x;
    const int lane = tid & 63;
    const int wid = tid >> 6;
    const int g = lane >> 4, c = lane & 15;
    const int wr = wid >> 1, wc = wid & 1;
    const int m0 = blockIdx.x * 128, n0 = blockIdx.y * 128;

    const f32x4 fz = {0.f, 0.f, 0.f, 0.f};
    f32x4 acc[4][4];
#pragma unroll
    for (int m = 0; m < 4; ++m)
#pragma unroll
        for (int n = 0; n < 4; ++n) acc[m][n] = fz;

    for (int kt = 0; kt < 16; ++kt) {
        const int k0 = kt * 64;
        __syncthreads();
#pragma unroll
        for (int st = 0; st < 4; ++st) {
            int ci = st * 256 + tid;
            int r = ci >> 3;
            int cc = (ci & 7) << 3;             // linear source column (no swizzle)
            gld16(A + (m0 + r) * 1024 + k0 + cc, (char*)As + ci * 16);
            gld16(Bt + (n0 + r) * 1024 + k0 + cc, (char*)Bs + ci * 16);
        }
        __syncthreads();
#pragma unroll
        for (int kk = 0; kk < 2; ++kk) {
            bf16x8 af[4], bfr[4];
#pragma unroll
            for (int m = 0; m < 4; ++m) {
                int row = wr * 64 + m * 16 + c;
                af[m] = *(const bf16x8*)&As[row * 64 + kk * 32 + g * 8];
            }
#pragma unroll
            for (int n = 0; n < 4; ++n) {
                int row = wc * 64 + n * 16 + c;
                bfr[n] = *(const bf16x8*)&Bs[row * 64 + kk * 32 + g * 8];
            }
#pragma unroll
            for (int m = 0; m < 4; ++m)
#pragma unroll
                for (int n = 0; n < 4; ++n)
                    acc[m][n] = __builtin_amdgcn_mfma_f32_16x16x32_bf16(af[m], bfr[n], acc[m][n], 0, 0, 0);
        }
    }

#pragma unroll
    for (int n = 0; n < 4; ++n) {
        const int col = n0 + wc * 64 + n * 16 + c;
        float bv = 0.f;
        if (MODE != 0) bv = bias[col];
#pragma unroll
        for (int m = 0; m < 4; ++m) {
            const int row0 = m0 + wr * 64 + m * 16 + g * 4;
#pragma unroll
            for (int i = 0; i < 4; ++i) {
                const int row = row0 + i;
                float val = acc[m][n][i];
                if (MODE == 0) {
                    short* qkv = (short*)outp;
                    int which = col >> 10;
                    int hc = col & 1023;
                    int dst = which * 8388608 +
                              (((row >> 10) * 16 + (hc >> 6)) * 1024 + (row & 1023)) * 64 + (hc & 63);
                    qkv[dst] = f2bf(val);
                } else if (MODE == 1) {
                    ((short*)outp)[row * 1024 + col] = f2bf(val + bv);
                } else {
                    ((float*)outp)[row * 1024 + col] = fmaxf(val + bv, 0.f);
                }
            }
        }
    }
}

// ---------------- causal flash attention v2.1 ----------------
// grid (T/128, B*H), 512 threads / 8 waves. Each wave: 16 q-rows. K tiles of 128.
// All LDS buffers XOR-swizzled (same formula on write and read; reg-staged).
// launch_bounds (512,2): round-3's (512,4) capped VGPR at 64 -> 80MB of scratch
// spills per dispatch (WRITE_SIZE 96MB vs 16.5MB output). 256-cap removes spills.
__global__ __launch_bounds__(512, 2) void attn_kernel(const short* __restrict__ qp,
                                                      const short* __restrict__ kp,
                                                      const short* __restrict__ vp,
                                                      short* __restrict__ ao) {
    __shared__ short Ks[128 * 64];     // row t: 128B rows, swz ((r&7)<<4)
    __shared__ short Vt[64 * 128];     // row d: 256B rows, swz (((d&7)^(d>>3))<<4)
    __shared__ short Ps[8][16 * 128];  // per-wave, row q: 256B rows, swz ((q&7)<<4)
    const float SCALE = 0.125f * 1.44269504088896340736f;  // 1/sqrt(64) * log2(e)
    const int tid = threadIdx.x;
    const int lane = tid & 63;
    const int wid = tid >> 6;
    const int g = lane >> 4, c = lane & 15;
    const int qt = blockIdx.x, bh = blockIdx.y;
    const int q0 = qt * 128;
    const int base = bh * 65536;  // 1024*64

    // Q A-fragments hoisted to registers (rows q0 + wid*16 + c)
    const int qrow = q0 + wid * 16 + c;
    bf16x8 qf0 = *(const bf16x8*)(qp + base + qrow * 64 + g * 8);
    bf16x8 qf1 = *(const bf16x8*)(qp + base + qrow * 64 + 32 + g * 8);

    const f32x4 fz = {0.f, 0.f, 0.f, 0.f};
    f32x4 accO[4];
#pragma unroll
    for (int n = 0; n < 4; ++n) accO[n] = fz;
    float mrow[4], lrow[4];
#pragma unroll
    for (int i = 0; i < 4; ++i) { mrow[i] = -1e30f; lrow[i] = 0.f; }

    // V staging decomposition: thread handles 4t x 4d
    const int vt0 = (tid >> 4) * 4;   // 0..124
    const int vd0 = (tid & 15) * 4;   // 0..60

    const int nkt = qt + 1;
    for (int kt = 0; kt < nkt; ++kt) {
        __syncthreads();  // previous iteration's Ks/Vt reads complete
        // ---- stage K (reg -> LDS, swizzled) ----
#pragma unroll
        for (int it = 0; it < 2; ++it) {
            int ci = it * 512 + tid;
            int r = ci >> 3;
            int cc = (ci & 7) << 3;
            bf16x8 kv = *(const bf16x8*)(kp + base + (kt * 128 + r) * 64 + cc);
            *(bf16x8*)((char*)Ks + r * 128 + ((cc * 2) ^ ((r & 7) << 4))) = kv;
        }
        // ---- stage V transposed (4x4 register transpose, b64 stores) ----
        {
            short4v vv[4];
#pragma unroll
            for (int j = 0; j < 4; ++j)
                vv[j] = *(const short4v*)(vp + base + (kt * 128 + vt0 + j) * 64 + vd0);
#pragma unroll
            for (int i = 0; i < 4; ++i) {
                short4v w; w[0] = vv[0][i]; w[1] = vv[1][i]; w[2] = vv[2][i]; w[3] = vv[3][i];
                int d = vd0 + i;
                int swz = ((d & 7) ^ (d >> 3)) << 4;
                *(short4v*)((char*)Vt + d * 256 + ((vt0 * 2) ^ swz)) = w;
            }
        }
        __syncthreads();  // staging visible to all waves

        // ---- S = Q K^T  (16 q-rows x 128 keys per wave) ----
        f32x4 s[8];
#pragma unroll
        for (int n = 0; n < 8; ++n) {
            s[n] = fz;
            int row = n * 16 + c;
            int swz = (row & 7) << 4;
            bf16x8 kf0 = *(const bf16x8*)((const char*)Ks + row * 128 + ((g * 16) ^ swz));
            bf16x8 kf1 = *(const bf16x8*)((const char*)Ks + row * 128 + ((64 + g * 16) ^ swz));
            s[n] = __builtin_amdgcn_mfma_f32_16x16x32_bf16(qf0, kf0, s[n], 0, 0, 0);
            s[n] = __builtin_amdgcn_mfma_f32_16x16x32_bf16(qf1, kf1, s[n], 0, 0, 0);
        }

        // ---- scale + causal mask + per-row max ----
        const int qg0 = q0 + wid * 16 + g * 4;
        float pm[4];
#pragma unroll
        for (int i = 0; i < 4; ++i) pm[i] = -1e30f;
#pragma unroll
        for (int n = 0; n < 8; ++n) {
            int kg = kt * 128 + n * 16 + c;
#pragma unroll
            for (int i = 0; i < 4; ++i) {
                float vv = s[n][i] * SCALE;
                vv = (kg <= qg0 + i) ? vv : -1e30f;
                s[n][i] = vv;
                pm[i] = fmaxf(pm[i], vv);
            }
        }
#pragma unroll
        for (int off = 1; off < 16; off <<= 1)
#pragma unroll
            for (int i = 0; i < 4; ++i)
                pm[i] = fmaxf(pm[i], __shfl_xor(pm[i], off));

        // ---- online softmax update ----
        float rs[4];
#pragma unroll
        for (int i = 0; i < 4; ++i) {
            float mnew = fmaxf(mrow[i], pm[i]);
            float corr = exp2f(mrow[i] - mnew);
            mrow[i] = mnew;
            lrow[i] *= corr;
            rs[i] = 0.f;
#pragma unroll
            for (int n = 0; n < 4; ++n) accO[n][i] *= corr;
        }
#pragma unroll
        for (int n = 0; n < 8; ++n)
#pragma unroll
            for (int i = 0; i < 4; ++i) {
                float pv = exp2f(s[n][i] - mrow[i]);
                s[n][i] = pv;
                rs[i] += pv;
            }
#pragma unroll
        for (int off = 1; off < 16; off <<= 1)
#pragma unroll
            for (int i = 0; i < 4; ++i)
                rs[i] += __shfl_xor(rs[i], off);
#pragma unroll
        for (int i = 0; i < 4; ++i) lrow[i] += rs[i];

        // ---- write P to per-wave LDS [q][t] (swizzled scalar stores) ----
#pragma unroll
        for (int n = 0; n < 8; ++n) {
            int t = n * 16 + c;
#pragma unroll
            for (int i = 0; i < 4; ++i) {
                int q = g * 4 + i;
                *(short*)((char*)&Ps[wid][0] + q * 256 + ((t * 2) ^ ((q & 7) << 4))) = f2bf(s[n][i]);
            }
        }

        // ---- O += P @ V ----
#pragma unroll
        for (int ks = 0; ks < 4; ++ks) {
            bf16x8 paf = *(const bf16x8*)((const char*)&Ps[wid][0] +
                                          c * 256 + ((ks * 64 + g * 16) ^ ((c & 7) << 4)));
#pragma unroll
            for (int n = 0; n < 4; ++n) {
                int d = n * 16 + c;
                int swz = ((d & 7) ^ (d >> 3)) << 4;
                bf16x8 vf = *(const bf16x8*)((const char*)Vt + d * 256 + ((ks * 64 + g * 16) ^ swz));
                accO[n] = __builtin_amdgcn_mfma_f32_16x16x32_bf16(paf, vf, accO[n], 0, 0, 0);
            }
        }
    }

    // epilogue: normalize, store bf16 to [B, T, H*64+d]
    const int b = bh >> 4, h = bh & 15;
#pragma unroll
    for (int n = 0; n < 4; ++n)
#pragma unroll
        for (int i = 0; i < 4; ++i) {
            int t = q0 + wid * 16 + g * 4 + i;
            float o = accO[n][i] / lrow[i];
            ao[(b * 1024 + t) * 1024 + h * 64 + n * 16 + c] = f2bf(o);
        }
}

extern "C" void kernel_launch(void* const* d_in, const int* in_sizes, int n_in,
                              void* d_out, int out_size, void* d_ws, size_t ws_size,
                              hipStream_t stream) {
    const float* x  = (const float*)d_in[0];
    const float* Wq = (const float*)d_in[1];
    const float* Wk = (const float*)d_in[2];
    const float* Wv = (const float*)d_in[3];
    const float* Wo = (const float*)d_in[4];
    const float* bo = (const float*)d_in[5];
    const float* W1 = (const float*)d_in[6];
    const float* b1 = (const float*)d_in[7];

    char* ws = (char*)d_ws;
    short* xb    = (short*)(ws + 0);          // 16.78 MB  [8192][1024] bf16
    short* wqkvT = (short*)(ws + 16777216);   //  6.29 MB  [3072][1024] bf16 (Wq^T|Wk^T|Wv^T)
    short* woT   = (short*)(ws + 23068672);   //  2.10 MB
    short* w1T   = (short*)(ws + 25165824);   //  2.10 MB
    short* qb    = (short*)(ws + 27262976);   // 3 x 16.78 MB: q,k,v [B*H][T][64] bf16
    short* kb    = qb + 8388608;
    short* vb    = qb + 16777216;
    short* ao    = xb;                        // reuse: attention out [8192][1024] bf16
    short* o2    = qb;                        // reuse: Wo out [8192][1024] bf16

    cvt_x_kernel<<<4096, 256, 0, stream>>>(x, xb);
    wtrans_kernel<<<dim3(16, 16), 256, 0, stream>>>(Wq, wqkvT);
    wtrans_kernel<<<dim3(16, 16), 256, 0, stream>>>(Wk, wqkvT + 1048576);
    wtrans_kernel<<<dim3(16, 16), 256, 0, stream>>>(Wv, wqkvT + 2097152);
    wtrans_kernel<<<dim3(16, 16), 256, 0, stream>>>(Wo, woT);
    wtrans_kernel<<<dim3(16, 16), 256, 0, stream>>>(W1, w1T);

    gemm_bt<0><<<dim3(64, 24), 256, 0, stream>>>(xb, wqkvT, nullptr, (void*)qb);
    attn_kernel<<<dim3(8, 128), 512, 0, stream>>>(qb, kb, vb, ao);
    gemm_bt<1><<<dim3(64, 8), 256, 0, stream>>>(ao, woT, bo, (void*)o2);
    gemm_bt<2><<<dim3(64, 8), 256, 0, stream>>>(o2, w1T, b1, d_out);
}

// Round 5
// 210.348 us; speedup vs baseline: 1.6980x; 1.2986x over previous
//
#include <hip/hip_runtime.h>

typedef __bf16 bf16x8 __attribute__((ext_vector_type(8)));
typedef float f32x4 __attribute__((ext_vector_type(4)));
typedef short short4v __attribute__((ext_vector_type(4)));
typedef short short8v __attribute__((ext_vector_type(8)));

#define DEVI static __device__ __forceinline__

// fp32 -> bf16 bits, round-to-nearest-even
DEVI short f2bf(float f) {
    union { float f; unsigned u; } x; x.f = f;
    unsigned r = (x.u + 0x7fffu + ((x.u >> 16) & 1u)) >> 16;
    return (short)r;
}

// async global -> LDS, 16B per lane (dest linear: wave-uniform base + lane*16)
DEVI void gld16(const void* g, void* l) {
    __builtin_amdgcn_global_load_lds(
        (const __attribute__((address_space(1))) unsigned int*)g,
        (__attribute__((address_space(3))) unsigned int*)l, 16, 0, 0);
}

// ---------------- x fp32 -> bf16 ----------------
__global__ __launch_bounds__(256) void cvt_x_kernel(const float* __restrict__ x,
                                                    short* __restrict__ xb) {
    int i = (blockIdx.x * 256 + threadIdx.x) * 8;
    f32x4 a = *(const f32x4*)(x + i);
    f32x4 b = *(const f32x4*)(x + i + 4);
    short8v o;
    o[0]=f2bf(a[0]); o[1]=f2bf(a[1]); o[2]=f2bf(a[2]); o[3]=f2bf(a[3]);
    o[4]=f2bf(b[0]); o[5]=f2bf(b[1]); o[6]=f2bf(b[2]); o[7]=f2bf(b[3]);
    *(short8v*)(xb + i) = o;
}

// ------------- weight [K=1024][N=1024] fp32 -> [N][K] bf16 (transpose) -------------
__global__ __launch_bounds__(256) void wtrans_kernel(const float* __restrict__ w,
                                                     short* __restrict__ wt) {
    __shared__ float t[64][68];
    const int tid = threadIdx.x;
    const int k0 = blockIdx.x * 64, n0 = blockIdx.y * 64;
#pragma unroll
    for (int it = 0; it < 4; ++it) {
        int r = (tid >> 4) + it * 16;
        int cc = (tid & 15) * 4;
        f32x4 vv = *(const f32x4*)(w + (k0 + r) * 1024 + n0 + cc);
        *(f32x4*)&t[r][cc] = vv;
    }
    __syncthreads();
#pragma unroll
    for (int it = 0; it < 4; ++it) {
        int n = (tid >> 4) + it * 16;
        int kc = (tid & 15) * 4;
        short4v o;
        o[0] = f2bf(t[kc + 0][n]);
        o[1] = f2bf(t[kc + 1][n]);
        o[2] = f2bf(t[kc + 2][n]);
        o[3] = f2bf(t[kc + 3][n]);
        *(short4v*)(wt + (n0 + n) * 1024 + k0 + kc) = o;
    }
}

// ---------------- GEMM: C[M,N] = A[M,1024] @ Bt[N,1024]^T (m97 structure, linear LDS) --------
// MODE 0: scatter bf16 to q/k/v [which][b*16+h][t][64]   (outp = qkv base)
// MODE 1: bf16 out = acc + bias
// MODE 2: fp32 out = relu(acc + bias)
template<int MODE>
__global__ __launch_bounds__(256, 2) void gemm_bt(const short* __restrict__ A,
                                                  const short* __restrict__ Bt,
                                                  const float* __restrict__ bias,
                                                  void* __restrict__ outp) {
    __shared__ short As[128 * 64];  // [row][k] linear, 64 shorts/row
    __shared__ short Bs[128 * 64];
    const int tid = threadIdx.x;
    const int lane = tid & 63;
    const int wid = tid >> 6;
    const int g = lane >> 4, c = lane & 15;
    const int wr = wid >> 1, wc = wid & 1;
    const int m0 = blockIdx.x * 128, n0 = blockIdx.y * 128;

    const f32x4 fz = {0.f, 0.f, 0.f, 0.f};
    f32x4 acc[4][4];
#pragma unroll
    for (int m = 0; m < 4; ++m)
#pragma unroll
        for (int n = 0; n < 4; ++n) acc[m][n] = fz;

    for (int kt = 0; kt < 16; ++kt) {
        const int k0 = kt * 64;
        __syncthreads();
#pragma unroll
        for (int st = 0; st < 4; ++st) {
            int ci = st * 256 + tid;
            int r = ci >> 3;
            int cc = (ci & 7) << 3;             // linear source column (no swizzle)
            gld16(A + (m0 + r) * 1024 + k0 + cc, (char*)As + ci * 16);
            gld16(Bt + (n0 + r) * 1024 + k0 + cc, (char*)Bs + ci * 16);
        }
        __syncthreads();
#pragma unroll
        for (int kk = 0; kk < 2; ++kk) {
            bf16x8 af[4], bfr[4];
#pragma unroll
            for (int m = 0; m < 4; ++m) {
                int row = wr * 64 + m * 16 + c;
                af[m] = *(const bf16x8*)&As[row * 64 + kk * 32 + g * 8];
            }
#pragma unroll
            for (int n = 0; n < 4; ++n) {
                int row = wc * 64 + n * 16 + c;
                bfr[n] = *(const bf16x8*)&Bs[row * 64 + kk * 32 + g * 8];
            }
#pragma unroll
            for (int m = 0; m < 4; ++m)
#pragma unroll
                for (int n = 0; n < 4; ++n)
                    acc[m][n] = __builtin_amdgcn_mfma_f32_16x16x32_bf16(af[m], bfr[n], acc[m][n], 0, 0, 0);
        }
    }

#pragma unroll
    for (int n = 0; n < 4; ++n) {
        const int col = n0 + wc * 64 + n * 16 + c;
        float bv = 0.f;
        if (MODE != 0) bv = bias[col];
#pragma unroll
        for (int m = 0; m < 4; ++m) {
            const int row0 = m0 + wr * 64 + m * 16 + g * 4;
#pragma unroll
            for (int i = 0; i < 4; ++i) {
                const int row = row0 + i;
                float val = acc[m][n][i];
                if (MODE == 0) {
                    short* qkv = (short*)outp;
                    int which = col >> 10;
                    int hc = col & 1023;
                    int dst = which * 8388608 +
                              (((row >> 10) * 16 + (hc >> 6)) * 1024 + (row & 1023)) * 64 + (hc & 63);
                    qkv[dst] = f2bf(val);
                } else if (MODE == 1) {
                    ((short*)outp)[row * 1024 + col] = f2bf(val + bv);
                } else {
                    ((float*)outp)[row * 1024 + col] = fmaxf(val + bv, 0.f);
                }
            }
        }
    }
}

// ---------------- causal flash attention v3 ----------------
// grid (4, B*H), 512 threads / 8 waves. Block handles q-tiles {bx, 7-bx}
// sequentially -> every block does exactly 9 K-tile iterations (load balance).
// K/V for tile kt+1 prefetched to regs while tile kt computes (T14).
// Causal mask applied only on the diagonal tile; off-diagonal QK n-tiles
// above the wave's rows are skipped on the diagonal.
__global__ __launch_bounds__(512, 2) void attn_kernel(const short* __restrict__ qp,
                                                      const short* __restrict__ kp,
                                                      const short* __restrict__ vp,
                                                      short* __restrict__ ao) {
    __shared__ short Ks[128 * 64];     // row t: 128B rows, swz ((r&7)<<4)
    __shared__ short Vt[64 * 128];     // row d: 256B rows, swz (((d&7)^(d>>3))<<4)
    __shared__ short Ps[8][16 * 128];  // per-wave, row q: 256B rows, swz ((q&7)<<4)
    const float SCALE = 0.125f * 1.44269504088896340736f;  // 1/sqrt(64) * log2(e)
    const int tid = threadIdx.x;
    const int lane = tid & 63;
    const int wid = tid >> 6;
    const int g = lane >> 4, c = lane & 15;
    const int bh = blockIdx.y;
    const int base = bh * 65536;  // 1024*64
    const int b = bh >> 4, h = bh & 15;

    // K staging indices (two 16B chunks per thread)
    const int r0 = tid >> 3, c0 = (tid & 7) << 3;
    const int r1 = 64 + r0;  // ci = 512+tid has same (ci&7)
    // V staging decomposition: thread handles 4t x 4d
    const int vt0 = (tid >> 4) * 4;   // 0..124
    const int vd0 = (tid & 15) * 4;   // 0..60

    const f32x4 fz = {0.f, 0.f, 0.f, 0.f};

    bf16x8 kreg0, kreg1;
    short4v vreg0, vreg1, vreg2, vreg3;

#pragma unroll 1
    for (int ph = 0; ph < 2; ++ph) {
        const int qt = ph ? (7 - blockIdx.x) : blockIdx.x;
        const int q0 = qt * 128;
        const int nkt = qt + 1;

        // Q A-fragments hoisted to registers (rows q0 + wid*16 + c)
        const int qrow = q0 + wid * 16 + c;
        bf16x8 qf0 = *(const bf16x8*)(qp + base + qrow * 64 + g * 8);
        bf16x8 qf1 = *(const bf16x8*)(qp + base + qrow * 64 + 32 + g * 8);

        f32x4 accO[4];
#pragma unroll
        for (int n = 0; n < 4; ++n) accO[n] = fz;
        float mrow[4], lrow[4];
#pragma unroll
        for (int i = 0; i < 4; ++i) { mrow[i] = -1e30f; lrow[i] = 0.f; }

        // prologue: load kt=0 K/V into regs
        kreg0 = *(const bf16x8*)(kp + base + r0 * 64 + c0);
        kreg1 = *(const bf16x8*)(kp + base + r1 * 64 + c0);
        vreg0 = *(const short4v*)(vp + base + (vt0 + 0) * 64 + vd0);
        vreg1 = *(const short4v*)(vp + base + (vt0 + 1) * 64 + vd0);
        vreg2 = *(const short4v*)(vp + base + (vt0 + 2) * 64 + vd0);
        vreg3 = *(const short4v*)(vp + base + (vt0 + 3) * 64 + vd0);

        for (int kt = 0; kt < nkt; ++kt) {
            __syncthreads();  // prev tile's (or prev phase's) LDS reads complete
            // ---- write staged K to LDS (swizzled) ----
            *(bf16x8*)((char*)Ks + r0 * 128 + ((c0 * 2) ^ ((r0 & 7) << 4))) = kreg0;
            *(bf16x8*)((char*)Ks + r1 * 128 + ((c0 * 2) ^ ((r1 & 7) << 4))) = kreg1;
            // ---- write staged V transposed (4x4 register transpose) ----
#pragma unroll
            for (int i = 0; i < 4; ++i) {
                short4v w; w[0] = vreg0[i]; w[1] = vreg1[i]; w[2] = vreg2[i]; w[3] = vreg3[i];
                int d = vd0 + i;
                int swz = ((d & 7) ^ (d >> 3)) << 4;
                *(short4v*)((char*)Vt + d * 256 + ((vt0 * 2) ^ swz)) = w;
            }
            // ---- prefetch next tile's K/V into regs (hides HBM under compute) ----
            if (kt + 1 < nkt) {
                const short* kp2 = kp + base + (kt + 1) * 8192;
                const short* vp2 = vp + base + (kt + 1) * 8192;
                kreg0 = *(const bf16x8*)(kp2 + r0 * 64 + c0);
                kreg1 = *(const bf16x8*)(kp2 + r1 * 64 + c0);
                vreg0 = *(const short4v*)(vp2 + (vt0 + 0) * 64 + vd0);
                vreg1 = *(const short4v*)(vp2 + (vt0 + 1) * 64 + vd0);
                vreg2 = *(const short4v*)(vp2 + (vt0 + 2) * 64 + vd0);
                vreg3 = *(const short4v*)(vp2 + (vt0 + 3) * 64 + vd0);
            }
            __syncthreads();  // staging visible to all waves

            const bool diag = (kt == nkt - 1);  // kt == qt
            const int nlim = diag ? (wid + 1) : 8;

            // ---- S = Q K^T ----
            f32x4 s[8];
#pragma unroll
            for (int n = 0; n < 8; ++n) {
                s[n] = fz;
                if (n < nlim) {
                    int row = n * 16 + c;
                    int swz = (row & 7) << 4;
                    bf16x8 kf0 = *(const bf16x8*)((const char*)Ks + row * 128 + ((g * 16) ^ swz));
                    bf16x8 kf1 = *(const bf16x8*)((const char*)Ks + row * 128 + ((64 + g * 16) ^ swz));
                    s[n] = __builtin_amdgcn_mfma_f32_16x16x32_bf16(qf0, kf0, s[n], 0, 0, 0);
                    s[n] = __builtin_amdgcn_mfma_f32_16x16x32_bf16(qf1, kf1, s[n], 0, 0, 0);
                }
            }

            // ---- scale (+ causal mask on diagonal tile only) + per-row max ----
            const int qg0 = q0 + wid * 16 + g * 4;
            float pm[4];
#pragma unroll
            for (int i = 0; i < 4; ++i) pm[i] = -1e30f;
            if (diag) {
#pragma unroll
                for (int n = 0; n < 8; ++n) {
                    int kg = kt * 128 + n * 16 + c;
#pragma unroll
                    for (int i = 0; i < 4; ++i) {
                        float vv = s[n][i] * SCALE;
                        vv = (kg <= qg0 + i) ? vv : -1e30f;
                        s[n][i] = vv;
                        pm[i] = fmaxf(pm[i], vv);
                    }
                }
            } else {
#pragma unroll
                for (int n = 0; n < 8; ++n)
#pragma unroll
                    for (int i = 0; i < 4; ++i) {
                        float vv = s[n][i] * SCALE;
                        s[n][i] = vv;
                        pm[i] = fmaxf(pm[i], vv);
                    }
            }
#pragma unroll
            for (int off = 1; off < 16; off <<= 1)
#pragma unroll
                for (int i = 0; i < 4; ++i)
                    pm[i] = fmaxf(pm[i], __shfl_xor(pm[i], off));

            // ---- online softmax update ----
            float rs[4];
#pragma unroll
            for (int i = 0; i < 4; ++i) {
                float mnew = fmaxf(mrow[i], pm[i]);
                float corr = exp2f(mrow[i] - mnew);
                mrow[i] = mnew;
                lrow[i] *= corr;
                rs[i] = 0.f;
#pragma unroll
                for (int n = 0; n < 4; ++n) accO[n][i] *= corr;
            }
#pragma unroll
            for (int n = 0; n < 8; ++n)
#pragma unroll
                for (int i = 0; i < 4; ++i) {
                    float pv = exp2f(s[n][i] - mrow[i]);
                    s[n][i] = pv;
                    rs[i] += pv;
                }
#pragma unroll
            for (int off = 1; off < 16; off <<= 1)
#pragma unroll
                for (int i = 0; i < 4; ++i)
                    rs[i] += __shfl_xor(rs[i], off);
#pragma unroll
            for (int i = 0; i < 4; ++i) lrow[i] += rs[i];

            // ---- write P to per-wave LDS [q][t] (swizzled scalar stores) ----
#pragma unroll
            for (int n = 0; n < 8; ++n) {
                int t = n * 16 + c;
#pragma unroll
                for (int i = 0; i < 4; ++i) {
                    int q = g * 4 + i;
                    *(short*)((char*)&Ps[wid][0] + q * 256 + ((t * 2) ^ ((q & 7) << 4))) = f2bf(s[n][i]);
                }
            }

            // ---- O += P @ V ----
#pragma unroll
            for (int ks = 0; ks < 4; ++ks) {
                bf16x8 paf = *(const bf16x8*)((const char*)&Ps[wid][0] +
                                              c * 256 + ((ks * 64 + g * 16) ^ ((c & 7) << 4)));
#pragma unroll
                for (int n = 0; n < 4; ++n) {
                    int d = n * 16 + c;
                    int swz = ((d & 7) ^ (d >> 3)) << 4;
                    bf16x8 vf = *(const bf16x8*)((const char*)Vt + d * 256 + ((ks * 64 + g * 16) ^ swz));
                    accO[n] = __builtin_amdgcn_mfma_f32_16x16x32_bf16(paf, vf, accO[n], 0, 0, 0);
                }
            }
        }

        // ---- epilogue: normalize, store bf16 to [B, T, H*64+d] ----
#pragma unroll
        for (int n = 0; n < 4; ++n)
#pragma unroll
            for (int i = 0; i < 4; ++i) {
                int t = q0 + wid * 16 + g * 4 + i;
                float o = accO[n][i] / lrow[i];
                ao[(b * 1024 + t) * 1024 + h * 64 + n * 16 + c] = f2bf(o);
            }
    }
}

extern "C" void kernel_launch(void* const* d_in, const int* in_sizes, int n_in,
                              void* d_out, int out_size, void* d_ws, size_t ws_size,
                              hipStream_t stream) {
    const float* x  = (const float*)d_in[0];
    const float* Wq = (const float*)d_in[1];
    const float* Wk = (const float*)d_in[2];
    const float* Wv = (const float*)d_in[3];
    const float* Wo = (const float*)d_in[4];
    const float* bo = (const float*)d_in[5];
    const float* W1 = (const float*)d_in[6];
    const float* b1 = (const float*)d_in[7];

    char* ws = (char*)d_ws;
    short* xb    = (short*)(ws + 0);          // 16.78 MB  [8192][1024] bf16
    short* wqkvT = (short*)(ws + 16777216);   //  6.29 MB  [3072][1024] bf16 (Wq^T|Wk^T|Wv^T)
    short* woT   = (short*)(ws + 23068672);   //  2.10 MB
    short* w1T   = (short*)(ws + 25165824);   //  2.10 MB
    short* qb    = (short*)(ws + 27262976);   // 3 x 16.78 MB: q,k,v [B*H][T][64] bf16
    short* kb    = qb + 8388608;
    short* vb    = qb + 16777216;
    short* ao    = xb;                        // reuse: attention out [8192][1024] bf16
    short* o2    = qb;                        // reuse: Wo out [8192][1024] bf16

    cvt_x_kernel<<<4096, 256, 0, stream>>>(x, xb);
    wtrans_kernel<<<dim3(16, 16), 256, 0, stream>>>(Wq, wqkvT);
    wtrans_kernel<<<dim3(16, 16), 256, 0, stream>>>(Wk, wqkvT + 1048576);
    wtrans_kernel<<<dim3(16, 16), 256, 0, stream>>>(Wv, wqkvT + 2097152);
    wtrans_kernel<<<dim3(16, 16), 256, 0, stream>>>(Wo, woT);
    wtrans_kernel<<<dim3(16, 16), 256, 0, stream>>>(W1, w1T);

    gemm_bt<0><<<dim3(64, 24), 256, 0, stream>>>(xb, wqkvT, nullptr, (void*)qb);
    attn_kernel<<<dim3(4, 128), 512, 0, stream>>>(qb, kb, vb, ao);
    gemm_bt<1><<<dim3(64, 8), 256, 0, stream>>>(ao, woT, bo, (void*)o2);
    gemm_bt<2><<<dim3(64, 8), 256, 0, stream>>>(o2, w1T, b1, d_out);
}